// Round 6
// baseline (157.276 us; speedup 1.0000x reference)
//
#include <hip/hip_runtime.h>
#include <cfloat>

#define NN   1024
#define NE   16384
#define D0   128
#define EDIM 16
#define NH1  64
#define NOUT 40
#define KTOP 8
#define NEGINF (-1000000000.0f)
#define MAXDEG 64   // out-deg ~ Poisson(16), selected in-deg ~ Poisson(8); P(>64) negligible

// ---- workspace layout (bytes); cnt_src zeroed by 4KB memset, rest written-before-read ----
#define OFF_CNT   0u        // 1024 int (src list counts)  -- memset 4KB
#define OFF_SE    4096u     // NE f
#define OFF_A     69632u    // 1024 f
#define OFF_B     73728u    // 1024 f
#define OFF_SLOT  77824u    // 1024*64 int (per-src edge lists)
#define OFF_EM    339968u   // 8192 int (edge id per selection)
#define OFF_ND    372736u   // 8192 int (new_dst per selection)
#define OFF_H     405504u   // 1024*64 f (GENConv1 output)

__device__ __forceinline__ void amx(float& v, int& j, float ov, int oj) {
    if (ov > v || (ov == v && oj < j)) { v = ov; j = oj; }
}

// ============================================================================
// Kernel 0: prep (verified round-0 body). blocks 0..63: se[e]=ea[e]@w_e +
// scatter edge into per-src list; blocks 64..319: a,b row dots.
// Runs right after the poison fill -> absorbs any L3-drain tax (Model B probe).
// ============================================================================
__global__ __launch_bounds__(256) void prep_kernel(
    const float* __restrict__ x, const float* __restrict__ ea,
    const float* __restrict__ mlp_w, const int* __restrict__ ei,
    float* __restrict__ se, float* __restrict__ a, float* __restrict__ b,
    int* __restrict__ cnt_src, int* __restrict__ slot_src)
{
    const int bid = blockIdx.x, t = threadIdx.x;
    if (bid < 64) {
        int e = bid * 256 + t;
        float acc = 0.f;
        #pragma unroll
        for (int k = 0; k < EDIM; k++) acc += ea[e * EDIM + k] * mlp_w[2 * D0 + k];
        se[e] = acc;
        int s = ei[e];
        int p = atomicAdd(&cnt_src[s], 1);
        if (p < MAXDEG) slot_src[s * MAXDEG + p] = e;  // order nondeterministic; consumer is max/min
    } else {
        int lane = t & 63, wid = t >> 6;
        int row = (bid - 64) * 4 + wid;
        const float* xr = x + row * D0;
        float x0 = xr[lane], x1 = xr[64 + lane];
        float sa = x0 * mlp_w[lane]       + x1 * mlp_w[64 + lane];
        float sb = x0 * mlp_w[128 + lane] + x1 * mlp_w[192 + lane];
        for (int s2 = 32; s2; s2 >>= 1) { sa += __shfl_down(sa, s2); sb += __shfl_down(sb, s2); }
        if (lane == 0) { a[row] = sa; b[row] = sb; }
    }
}

// ============================================================================
// Kernel 1: per-row softmax + gumbel + top-8 from PREBUILT lists (no scan).
// 1024 blocks x 512 threads; round-5's verified reg-top8 + wave0-merge tail.
// ============================================================================
__global__ __launch_bounds__(512) void rowtopk_kernel(
    const float* __restrict__ se, const float* __restrict__ a,
    const float* __restrict__ b, const float* __restrict__ u,
    const float* __restrict__ mlp_b, const int* __restrict__ ei,
    const int* __restrict__ cnt_src, const int* __restrict__ slot_src,
    const float* __restrict__ x, const float* __restrict__ ea,
    const float* __restrict__ c1w1,   // last three: prefetch-only (warm L2/L3 for gc1)
    int* __restrict__ nd, int* __restrict__ em)
{
    __shared__ int   idmx[NN];      // max edge id per dst, -1 = none
    __shared__ int   idmn[NN];      // min edge id per dst
    __shared__ float wred[16];      // [0..7] max, [8..15] sum
    __shared__ float candv[64];
    __shared__ int   candj[64];
    const int i = blockIdx.x, t = threadIdx.x;
    const int lane = t & 63, w = t >> 6;          // wave 0..7

    // ---- prefetch u (HBM-cold) into regs ----
    float uval[2];
    uval[0] = u[i * NN + w * 128 + lane];
    uval[1] = u[i * NN + w * 128 + 64 + lane];

    #pragma unroll
    for (int q = 0; q < 2; q++) {
        int j = t + q * 512;
        idmx[j] = -1; idmn[j] = 0x7FFFFFFF;
    }
    __syncthreads();

    // ---- rebuild idmx/idmn from this row's prebuilt list (~16 entries) ----
    const int deg = min(cnt_src[i], MAXDEG);
    if (t < deg) {
        int e = slot_src[i * MAXDEG + t];
        int dj = ei[NE + e];
        atomicMax(&idmx[dj], e);
        atomicMin(&idmn[dj], e);
    }
    __syncthreads();

    // ---- scores straight into registers: wave w owns cols [w*128, w*128+128) ----
    const float arb = a[i] + mlp_b[0];
    float val[2];
    #pragma unroll
    for (int q = 0; q < 2; q++) {
        int j = w * 128 + q * 64 + lane;
        int id = idmx[j];
        val[q] = (id >= 0) ? (arb + b[j] + se[id]) : NEGINF;
    }

    float lm = fmaxf(val[0], val[1]);
    for (int s2 = 32; s2; s2 >>= 1) lm = fmaxf(lm, __shfl_down(lm, s2));
    if (lane == 0) wred[w] = lm;
    __syncthreads();
    float rowmax = wred[0];
    #pragma unroll
    for (int q = 1; q < 8; q++) rowmax = fmaxf(rowmax, wred[q]);
    const bool noedge = (rowmax == NEGINF);

    float ls = 0.f;
    #pragma unroll
    for (int q = 0; q < 2; q++) {
        float ev = noedge ? 1.0f : ((val[q] == NEGINF) ? 0.0f : expf(val[q] - rowmax));
        val[q] = ev; ls += ev;
    }
    for (int s2 = 32; s2; s2 >>= 1) ls += __shfl_down(ls, s2);
    if (lane == 0) wred[8 + w] = ls;   // disjoint slots
    __syncthreads();
    float rsum = wred[8];
    #pragma unroll
    for (int q = 1; q < 8; q++) rsum += wred[8 + q];

    // ---- gumbel: val = z + g (softmax monotone -> same top-k) ----
    #pragma unroll
    for (int q = 0; q < 2; q++) {
        float g = -logf(-logf(uval[q] + 1e-20f) + 1e-20f);
        val[q] = val[q] / rsum + g;
    }

    // ---- per-wave top-8 over 128 columns (barrier-free, register-resident) ----
    for (int sel = 0; sel < KTOP; sel++) {
        float bv = -FLT_MAX; int bj = NN;
        amx(bv, bj, val[0], w * 128 + lane);
        amx(bv, bj, val[1], w * 128 + 64 + lane);
        for (int s2 = 32; s2; s2 >>= 1) {
            float ov = __shfl_down(bv, s2); int oj = __shfl_down(bj, s2);
            amx(bv, bj, ov, oj);
        }
        int wj = __shfl(bj, 0);
        if (lane == 0) { candv[w * KTOP + sel] = bv; candj[w * KTOP + sel] = bj; }
        if (w * 128 + lane == wj) val[0] = -FLT_MAX;
        if (w * 128 + 64 + lane == wj) val[1] = -FLT_MAX;
    }
    __syncthreads();

    if (w == 0) {
        // ---- wave 0: merge 64 candidates (all distinct j) into global top-8 ----
        float mv = candv[lane];
        int   mj = candj[lane];
        for (int sel = 0; sel < KTOP; sel++) {
            float bv = mv; int bj = mj;
            for (int s2 = 32; s2; s2 >>= 1) {
                float ov = __shfl_down(bv, s2); int oj = __shfl_down(bj, s2);
                amx(bv, bj, ov, oj);
            }
            int wj = __shfl(bj, 0);
            if (lane == 0) {
                int mn = idmn[wj];
                em[i * KTOP + sel] = (mn == 0x7FFFFFFF) ? 0 : mn;  // no edge -> argmax(all-false)=0
                nd[i * KTOP + sel] = wj;
            }
            if (mj == wj) mv = -FLT_MAX;
        }
    } else {
        // ---- waves 1-7 (idle during merge): warm L2/L3 for genconv1 ----
        float pf = 0.f;
        if (t < 192)       pf = x[i * D0 + (t - 64)];
        else if (t < 448)  pf = ea[i * 256 + (t - 192)];
        else if (t < 480)  pf = c1w1[i * 32 + (t - 448)];
        asm volatile("" :: "v"(pf));   // keep-alive (avoid DCE)
    }
}

// ============================================================================
// Kernel 2: GENConv1 fused. 1024 blocks (one dst row each) x 256 threads.
// (verified round-5 body)
// ============================================================================
__global__ __launch_bounds__(256) void genconv1_kernel(
    const float* __restrict__ x, const float* __restrict__ ea,
    const float* __restrict__ we_g, const float* __restrict__ be,
    const float* __restrict__ w1, const float* __restrict__ b1,
    const float* __restrict__ w2, const float* __restrict__ b2,
    const int* __restrict__ nd, const int* __restrict__ em,
    float* __restrict__ h)
{
    __shared__ int   slots[MAXDEG];
    __shared__ float eatt[MAXDEG * EDIM];
    __shared__ float arow[D0];
    __shared__ float t1s[2 * D0];
    __shared__ int   cnt_s;
    const int t = threadIdx.x;
    const int r = blockIdx.x;
    if (t == 0) cnt_s = 0;
    __syncthreads();

    const int4* nd4 = (const int4*)nd;
    #pragma unroll
    for (int q = 0; q < 8; q++) {
        int idx4 = t + q * 256;
        int4 v = nd4[idx4];
        int n0 = idx4 * 4;
        if (v.x == r) { int p = atomicAdd(&cnt_s, 1); if (p < MAXDEG) slots[p] = n0 + 0; }
        if (v.y == r) { int p = atomicAdd(&cnt_s, 1); if (p < MAXDEG) slots[p] = n0 + 1; }
        if (v.z == r) { int p = atomicAdd(&cnt_s, 1); if (p < MAXDEG) slots[p] = n0 + 2; }
        if (v.w == r) { int p = atomicAdd(&cnt_s, 1); if (p < MAXDEG) slots[p] = n0 + 3; }
    }
    __syncthreads();
    const int cnt = min(cnt_s, MAXDEG);
    if (t == 0) {  // ascending-n order (deterministic)
        for (int p = 1; p < cnt; p++) {
            int v = slots[p]; int q = p - 1;
            while (q >= 0 && slots[q] > v) { slots[q + 1] = slots[q]; q--; }
            slots[q + 1] = v;
        }
    }
    __syncthreads();
    for (int q = t; q < cnt * EDIM; q += 256)
        eatt[q] = ea[em[slots[q >> 4]] * EDIM + (q & 15)];
    __syncthreads();

    if (t < D0) {
        const int d = t;
        float wed[EDIM];
        #pragma unroll
        for (int k = 0; k < EDIM; k++) wed[k] = we_g[k * D0 + d];
        const float bed = be[d];

        float mxv = -FLT_MAX;
        for (int idx = 0; idx < cnt; idx++) {
            int src = slots[idx] >> 3;
            float ep = bed;
            #pragma unroll
            for (int k = 0; k < EDIM; k++) ep += eatt[idx * EDIM + k] * wed[k];
            float m = fmaxf(x[src * D0 + d] + ep, 0.f) + 1e-7f;
            mxv = fmaxf(mxv, m);
        }
        float den = 0.f, num = 0.f;
        for (int idx = 0; idx < cnt; idx++) {
            int src = slots[idx] >> 3;
            float ep = bed;
            #pragma unroll
            for (int k = 0; k < EDIM; k++) ep += eatt[idx * EDIM + k] * wed[k];
            float m = fmaxf(x[src * D0 + d] + ep, 0.f) + 1e-7f;
            float w = expf(m - mxv);
            den += w; num += w * m;
        }
        float agg = cnt ? num / (den > 0.f ? den : 1.f) : 0.f;
        arow[d] = agg + x[r * D0 + d];
    }
    __syncthreads();

    {
        float acc = b1[t];
        for (int k = 0; k < D0; k++) acc += arow[k] * w1[k * 2 * D0 + t];
        t1s[t] = fmaxf(acc, 0.f);
    }
    __syncthreads();
    if (t < NH1) {
        float acc = b2[t];
        for (int k = 0; k < 2 * D0; k++) acc += t1s[k] * w2[k * NH1 + t];
        h[r * NH1 + t] = fmaxf(acc, 0.f);
    }
}

// ============================================================================
// Kernel 3: GENConv2 + head. 1024 blocks (one dst row each) x 256 threads.
// (verified round-5 body)
// ============================================================================
__global__ __launch_bounds__(256) void genconv2_kernel(
    const float* __restrict__ h, const float* __restrict__ ea,
    const float* __restrict__ we_g, const float* __restrict__ be,
    const float* __restrict__ w1, const float* __restrict__ b1,
    const float* __restrict__ w2, const float* __restrict__ b2,
    const float* __restrict__ fcw, const float* __restrict__ fcb,
    const int* __restrict__ nd, const int* __restrict__ em,
    const int* __restrict__ mask, float* __restrict__ out)
{
    __shared__ int   slots[MAXDEG];
    __shared__ float eatt[MAXDEG * EDIM];
    __shared__ float arow[NH1];
    __shared__ float t2s[2 * NH1];
    __shared__ float h2s[NH1];
    __shared__ int   cnt_s;
    const int t = threadIdx.x;
    const int r = blockIdx.x;
    if (t == 0) cnt_s = 0;
    __syncthreads();

    const int4* nd4 = (const int4*)nd;
    #pragma unroll
    for (int q = 0; q < 8; q++) {
        int idx4 = t + q * 256;
        int4 v = nd4[idx4];
        int n0 = idx4 * 4;
        if (v.x == r) { int p = atomicAdd(&cnt_s, 1); if (p < MAXDEG) slots[p] = n0 + 0; }
        if (v.y == r) { int p = atomicAdd(&cnt_s, 1); if (p < MAXDEG) slots[p] = n0 + 1; }
        if (v.z == r) { int p = atomicAdd(&cnt_s, 1); if (p < MAXDEG) slots[p] = n0 + 2; }
        if (v.w == r) { int p = atomicAdd(&cnt_s, 1); if (p < MAXDEG) slots[p] = n0 + 3; }
    }
    __syncthreads();
    const int cnt = min(cnt_s, MAXDEG);
    if (t == 0) {
        for (int p = 1; p < cnt; p++) {
            int v = slots[p]; int q = p - 1;
            while (q >= 0 && slots[q] > v) { slots[q + 1] = slots[q]; q--; }
            slots[q + 1] = v;
        }
    }
    __syncthreads();
    for (int q = t; q < cnt * EDIM; q += 256)
        eatt[q] = ea[em[slots[q >> 4]] * EDIM + (q & 15)];
    __syncthreads();

    if (t < NH1) {
        const int d = t;
        float wed[EDIM];
        #pragma unroll
        for (int k = 0; k < EDIM; k++) wed[k] = we_g[k * NH1 + d];
        const float bed = be[d];

        float mxv = -FLT_MAX;
        for (int idx = 0; idx < cnt; idx++) {
            int src = slots[idx] >> 3;
            float ep = bed;
            #pragma unroll
            for (int k = 0; k < EDIM; k++) ep += eatt[idx * EDIM + k] * wed[k];
            float m = fmaxf(h[src * NH1 + d] + ep, 0.f) + 1e-7f;
            mxv = fmaxf(mxv, m);
        }
        float den = 0.f, num = 0.f;
        for (int idx = 0; idx < cnt; idx++) {
            int src = slots[idx] >> 3;
            float ep = bed;
            #pragma unroll
            for (int k = 0; k < EDIM; k++) ep += eatt[idx * EDIM + k] * wed[k];
            float m = fmaxf(h[src * NH1 + d] + ep, 0.f) + 1e-7f;
            float w = expf(m - mxv);
            den += w; num += w * m;
        }
        float agg = cnt ? num / (den > 0.f ? den : 1.f) : 0.f;
        arow[d] = agg + h[r * NH1 + d];
    }
    __syncthreads();

    if (t < 2 * NH1) {
        float acc = b1[t];
        for (int k = 0; k < NH1; k++) acc += arow[k] * w1[k * 2 * NH1 + t];
        t2s[t] = fmaxf(acc, 0.f);
    }
    __syncthreads();
    if (t < NH1) {
        float acc = b2[t];
        for (int k = 0; k < 2 * NH1; k++) acc += t2s[k] * w2[k * NH1 + t];
        h2s[t] = fmaxf(acc, 0.f);
    }
    __syncthreads();
    if (t < NOUT) {
        float acc = fcb[t];
        for (int k = 0; k < NH1; k++) acc += h2s[k] * fcw[k * NOUT + t];
        out[r * NOUT + t] = (mask[r] != 0) ? acc : 0.f;
    }
}

extern "C" void kernel_launch(void* const* d_in, const int* in_sizes, int n_in,
                              void* d_out, int out_size, void* d_ws, size_t ws_size,
                              hipStream_t stream) {
    const float* x      = (const float*)d_in[0];
    const float* ea     = (const float*)d_in[1];
    const float* u      = (const float*)d_in[2];
    const float* mlp_w  = (const float*)d_in[3];
    const float* mlp_b  = (const float*)d_in[4];
    const float* c1_we  = (const float*)d_in[5];
    const float* c1_be  = (const float*)d_in[6];
    const float* c1_w1  = (const float*)d_in[7];
    const float* c1_b1  = (const float*)d_in[8];
    const float* c1_w2  = (const float*)d_in[9];
    const float* c1_b2  = (const float*)d_in[10];
    const float* c2_we  = (const float*)d_in[11];
    const float* c2_be  = (const float*)d_in[12];
    const float* c2_w1  = (const float*)d_in[13];
    const float* c2_b1  = (const float*)d_in[14];
    const float* c2_w2  = (const float*)d_in[15];
    const float* c2_b2  = (const float*)d_in[16];
    const float* fc_w   = (const float*)d_in[17];
    const float* fc_b   = (const float*)d_in[18];
    const int*   ei     = (const int*)d_in[20];
    const int*   mask   = (const int*)d_in[21];

    char* ws = (char*)d_ws;
    int*   cnt_src = (int*)(ws + OFF_CNT);
    float* se      = (float*)(ws + OFF_SE);
    float* a       = (float*)(ws + OFF_A);
    float* b       = (float*)(ws + OFF_B);
    int*   slot_s  = (int*)(ws + OFF_SLOT);
    int*   em      = (int*)(ws + OFF_EM);
    int*   nd      = (int*)(ws + OFF_ND);
    float* h       = (float*)(ws + OFF_H);
    float* out     = (float*)d_out;

    hipMemsetAsync(ws + OFF_CNT, 0, 4096, stream);   // cnt_src only
    prep_kernel<<<320, 256, 0, stream>>>(x, ea, mlp_w, ei, se, a, b, cnt_src, slot_s);
    rowtopk_kernel<<<NN, 512, 0, stream>>>(se, a, b, u, mlp_b, ei, cnt_src, slot_s,
                                           x, ea, c1_w1, nd, em);
    genconv1_kernel<<<NN, 256, 0, stream>>>(x, ea, c1_we, c1_be, c1_w1, c1_b1, c1_w2, c1_b2,
                                            nd, em, h);
    genconv2_kernel<<<NN, 256, 0, stream>>>(h, ea, c2_we, c2_be, c2_w1, c2_b1, c2_w2, c2_b2,
                                            fc_w, fc_b, nd, em, mask, out);
}